// Round 8
// baseline (804.979 us; speedup 1.0000x reference)
//
#include <hip/hip_runtime.h>
#include <hip/hip_bf16.h>
#include <math.h>

#define N_NODES 50000
#define N_EDGES 800000
#define IN_FEAT 8
#define HDIM 128
#define NLAYERS 6
#define NUM_GRAPHS 64
#define EPS_MSG 1e-7f
#define EPS_SM 1e-16f
#define LN_EPS 1e-5f
#define SCAN_NB 49   // ceil(50000/1024)

typedef __attribute__((ext_vector_type(8))) short short8;
typedef __attribute__((ext_vector_type(4))) float floatx4;
typedef __attribute__((ext_vector_type(4))) unsigned short ushort4v;

__device__ __forceinline__ ushort f2bf(float x) {
    __hip_bfloat16 h = __float2bfloat16(x);
    return *reinterpret_cast<ushort*>(&h);
}
__device__ __forceinline__ float bf2f(ushort u) {
    unsigned int v = ((unsigned int)u) << 16;
    return __uint_as_float(v);
}

// ---------------- node encoder + LN + ReLU (layer 0): X, Hb ----------------
__global__ void k_encode_ln(const float* __restrict__ xin, const float* __restrict__ W,
                            const float* __restrict__ bias, const float* __restrict__ g0,
                            const float* __restrict__ b0, float* __restrict__ X,
                            ushort2* __restrict__ Hb) {
    __shared__ float sW[IN_FEAT * HDIM];
    int tid = threadIdx.x;
    int wid = tid >> 6, lane = tid & 63;
    for (int i = tid; i < IN_FEAT * HDIM; i += 256) sW[i] = W[i];
    __syncthreads();
    int n = blockIdx.x * 4 + wid;
    if (n >= N_NODES) return;
    int c0 = 2 * lane, c1 = 2 * lane + 1;
    float a0 = bias[c0], a1 = bias[c1];
#pragma unroll
    for (int f = 0; f < IN_FEAT; ++f) {
        float xf = xin[n * IN_FEAT + f];
        a0 += xf * sW[f * HDIM + c0];
        a1 += xf * sW[f * HDIM + c1];
    }
    float2 xv; xv.x = a0; xv.y = a1;
    *(float2*)(X + (size_t)n * HDIM + c0) = xv;
    float s = a0 + a1, sq = a0 * a0 + a1 * a1;
#pragma unroll
    for (int off = 32; off; off >>= 1) {
        s += __shfl_xor(s, off, 64);
        sq += __shfl_xor(sq, off, 64);
    }
    float mean = s * (1.f / 128.f);
    float var = sq * (1.f / 128.f) - mean * mean;
    float inv = rsqrtf(var + LN_EPS);
    float h0 = (a0 - mean) * inv * g0[c0] + b0[c0];
    float h1 = (a1 - mean) * inv * g0[c1] + b0[c1];
    ushort2 o;
    o.x = f2bf(fmaxf(h0, 0.f));
    o.y = f2bf(fmaxf(h1, 0.f));
    Hb[(size_t)n * 64 + lane] = o;
}

// ---------------- CSR build ----------------
__global__ void k_hist(const int* __restrict__ dst, int* __restrict__ deg) {
    int i = blockIdx.x * blockDim.x + threadIdx.x;
    if (i < N_EDGES) atomicAdd(&deg[dst[i]], 1);
}

__global__ void k_bsum(const int* __restrict__ deg, int* __restrict__ bsum) {
    int i = blockIdx.x * 1024 + threadIdx.x;
    int v = (i < N_NODES) ? deg[i] : 0;
#pragma unroll
    for (int off = 32; off; off >>= 1) v += __shfl_xor(v, off, 64);
    __shared__ int wsum[16];
    int wid = threadIdx.x >> 6;
    if ((threadIdx.x & 63) == 0) wsum[wid] = v;
    __syncthreads();
    if (threadIdx.x < 16) {
        int s = wsum[threadIdx.x];
#pragma unroll
        for (int off = 8; off; off >>= 1) s += __shfl_xor(s, off, 16);
        if (threadIdx.x == 0) bsum[blockIdx.x] = s;
    }
}

__global__ void k_scan_small(int* __restrict__ bsum) {
    int lane = threadIdx.x;  // 0..63
    int orig = (lane < SCAN_NB) ? bsum[lane] : 0;
    int v = orig;
#pragma unroll
    for (int off = 1; off < 64; off <<= 1) {
        int u = __shfl_up(v, off, 64);
        if (lane >= off) v += u;
    }
    if (lane < SCAN_NB) bsum[lane] = v - orig;  // exclusive
}

__global__ void k_scan_final(const int* __restrict__ deg, const int* __restrict__ bsum,
                             int* __restrict__ row_ptr, int* __restrict__ cursor) {
    __shared__ int wsum[16];
    int i = blockIdx.x * 1024 + threadIdx.x;
    int t = threadIdx.x;
    int lane = t & 63, wid = t >> 6;
    int orig = (i < N_NODES) ? deg[i] : 0;
    int v = orig;
#pragma unroll
    for (int off = 1; off < 64; off <<= 1) {
        int u = __shfl_up(v, off, 64);
        if (lane >= off) v += u;
    }
    if (lane == 63) wsum[wid] = v;
    __syncthreads();
    if (t < 16) {
        int s = wsum[t];
#pragma unroll
        for (int off = 1; off < 16; off <<= 1) {
            int u = __shfl_up(s, off, 16);
            if (t >= off) s += u;
        }
        wsum[t] = s;
    }
    __syncthreads();
    int base = bsum[blockIdx.x] + (wid ? wsum[wid - 1] : 0);
    int excl = base + v - orig;
    if (i < N_NODES) {
        row_ptr[i] = excl;
        cursor[i] = excl;
    }
    if (i == 0) row_ptr[N_NODES] = N_EDGES;
}

__global__ void k_scatter(const int* __restrict__ src, const int* __restrict__ dst,
                          int* __restrict__ cursor, ushort* __restrict__ csr_src) {
    int i = blockIdx.x * blockDim.x + threadIdx.x;
    if (i < N_EDGES) {
        int pos = atomicAdd(&cursor[dst[i]], 1);
        csr_src[pos] = (ushort)src[i];
    }
}

// ---------------- weight prefragment: fp32 -> bf16 MFMA B-frag layout ----------------
__global__ void k_prep(const float* __restrict__ W1, const float* __restrict__ W2,
                       ushort* __restrict__ Wp1, ushort* __restrict__ Wp2) {
    int idx = blockIdx.x * 256 + threadIdx.x;
    if (idx < 24576) {
        int lane = idx & 63;
        int frag = idx >> 6;
        int cf = frag & 15, kb = (frag >> 4) & 3, l = frag >> 6;
        const float* Wl = W1 + (size_t)l * 128 * 256;
        ushort* o = Wp1 + (size_t)idx * 8;
        int k0 = kb * 32 + (lane >> 4) * 8;
        int c = cf * 16 + (lane & 15);
#pragma unroll
        for (int j = 0; j < 8; ++j) o[j] = f2bf(Wl[(k0 + j) * 256 + c]);
    } else if (idx < 49152) {
        int i2 = idx - 24576;
        int lane = i2 & 63;
        int frag = i2 >> 6;
        int cf = frag & 7, kb = (frag >> 3) & 7, l = frag >> 6;
        const float* Wl = W2 + (size_t)l * 256 * 128;
        ushort* o = Wp2 + (size_t)i2 * 8;
        int k0 = kb * 32 + (lane >> 4) * 8;
        int c = cf * 16 + (lane & 15);
#pragma unroll
        for (int j = 0; j < 8; ++j) o[j] = f2bf(Wl[(k0 + j) * 128 + c]);
    }
}

// ---------------- softmax aggregation: pair-per-wave, 4ch/lane, U = aggr + h ----------------
// One wave per node. Lanes 0-31 handle even edges, 32-63 odd edges, 4 channels/lane (8B loads).
// No-shift exp valid: h bounded ~sqrt(127), exp(m*t) <= ~1e5 fp32-safe; softmax shift-invariant.
__global__ __launch_bounds__(256) void k_aggr(const ushort* __restrict__ Hh,
                                              const int* __restrict__ row_ptr,
                                              const ushort* __restrict__ csr,
                                              const float* __restrict__ t_all,
                                              int layer, ushort* __restrict__ U) {
    int tid = threadIdx.x;
    int wid = tid >> 6, lane = tid & 63;
    int n = blockIdx.x * 4 + wid;  // 12500*4 = 50000 exact
    float ts = t_all[layer] * 1.44269504f;  // fold log2e: exp(m t) = exp2(m ts)
    int beg = row_ptr[n], cnt = row_ptr[n + 1] - beg;
    int h = lane >> 5, l32 = lane & 31;
    unsigned boff = (unsigned)(l32 << 3);  // byte offset within 256B row
    float num0 = 0.f, num1 = 0.f, num2 = 0.f, num3 = 0.f;
    float den0 = 0.f, den1 = 0.f, den2 = 0.f, den3 = 0.f;
    int npairs = (cnt + 1) >> 1;
    int emax = beg + cnt - 1;

    auto LDI = [&](int p) -> ushort4v {
        int e = beg + 2 * p + h;
        e = (e < emax) ? e : emax;
        int sidx = (int)csr[e];
        return *(const ushort4v*)((const char*)Hh + (((size_t)(unsigned)sidx) << 8) + boff);
    };
    auto proc = [&](ushort4v v, int p) {
        float vm = (2 * p + h < cnt) ? 1.f : 0.f;
        float m0 = bf2f(v.x) + EPS_MSG, m1 = bf2f(v.y) + EPS_MSG;
        float m2 = bf2f(v.z) + EPS_MSG, m3 = bf2f(v.w) + EPS_MSG;
        float e0 = exp2f(m0 * ts) * vm, e1 = exp2f(m1 * ts) * vm;
        float e2 = exp2f(m2 * ts) * vm, e3 = exp2f(m3 * ts) * vm;
        den0 += e0; num0 = fmaf(m0, e0, num0);
        den1 += e1; num1 = fmaf(m1, e1, num1);
        den2 += e2; num2 = fmaf(m2, e2, num2);
        den3 += e3; num3 = fmaf(m3, e3, num3);
    };

    if (cnt > 0) {
        ushort4v p0, p1, p2, p3, p4, p5, p6, p7;
        p0 = LDI(0);
        if (npairs > 1) p1 = LDI(1);
        if (npairs > 2) p2 = LDI(2);
        if (npairs > 3) p3 = LDI(3);
        if (npairs > 4) p4 = LDI(4);
        if (npairs > 5) p5 = LDI(5);
        if (npairs > 6) p6 = LDI(6);
        if (npairs > 7) p7 = LDI(7);
        int p = 0;
        while (p + 8 <= npairs) {
            ushort4v c0 = p0, c1 = p1, c2 = p2, c3 = p3,
                     c4 = p4, c5 = p5, c6 = p6, c7 = p7;
            if (p + 8 < npairs)  p0 = LDI(p + 8);
            if (p + 9 < npairs)  p1 = LDI(p + 9);
            if (p + 10 < npairs) p2 = LDI(p + 10);
            if (p + 11 < npairs) p3 = LDI(p + 11);
            if (p + 12 < npairs) p4 = LDI(p + 12);
            if (p + 13 < npairs) p5 = LDI(p + 13);
            if (p + 14 < npairs) p6 = LDI(p + 14);
            if (p + 15 < npairs) p7 = LDI(p + 15);
            proc(c0, p); proc(c1, p + 1); proc(c2, p + 2); proc(c3, p + 3);
            proc(c4, p + 4); proc(c5, p + 5); proc(c6, p + 6); proc(c7, p + 7);
            p += 8;
        }
        int rem = npairs - p;
        if (rem > 0) proc(p0, p);
        if (rem > 1) proc(p1, p + 1);
        if (rem > 2) proc(p2, p + 2);
        if (rem > 3) proc(p3, p + 3);
        if (rem > 4) proc(p4, p + 4);
        if (rem > 5) proc(p5, p + 5);
        if (rem > 6) proc(p6, p + 6);
    }

    // combine even/odd halves: lane L and L+32 hold same channels
    num0 += __shfl_xor(num0, 32, 64); den0 += __shfl_xor(den0, 32, 64);
    num1 += __shfl_xor(num1, 32, 64); den1 += __shfl_xor(den1, 32, 64);
    num2 += __shfl_xor(num2, 32, 64); den2 += __shfl_xor(den2, 32, 64);
    num3 += __shfl_xor(num3, 32, 64); den3 += __shfl_xor(den3, 32, 64);

    if (h == 0) {
        ushort4v hv = *(const ushort4v*)((const char*)Hh + (((size_t)n) << 8) + boff);
        ushort4v o;
        o.x = f2bf(num0 / (den0 + EPS_SM) + bf2f(hv.x));
        o.y = f2bf(num1 / (den1 + EPS_SM) + bf2f(hv.y));
        o.z = f2bf(num2 / (den2 + EPS_SM) + bf2f(hv.z));
        o.w = f2bf(num3 / (den3 + EPS_SM) + bf2f(hv.w));
        *(ushort4v*)((char*)U + (((size_t)n) << 8) + boff) = o;
    }
}

// ---- fused MLP: X += W2^T(relu(LN(U@W1+b1)))+b2; optional epilogue LN+ReLU -> Hb(next layer) ----
__global__ __launch_bounds__(256) void k_mlp_fused(
    const ushort* __restrict__ U, float* __restrict__ X,
    const short8* __restrict__ Wp1, const short8* __restrict__ Wp2,
    const float* __restrict__ b1, const float* __restrict__ mg,
    const float* __restrict__ mb, const float* __restrict__ b2,
    const float* __restrict__ nlg, const float* __restrict__ nlb,
    ushort* __restrict__ HbOut, int writeHb) {
    __shared__ ushort sBuf[64 * 264];
    __shared__ float sStat[4][64][2];
    __shared__ float sMV[64][2];
    int tid = threadIdx.x;
    int w = tid >> 6, lane = tid & 63;
    int g = lane >> 4, c15 = lane & 15;
    int n0 = blockIdx.x * 64;

#pragma unroll
    for (int i = 0; i < 4; ++i) {
        int id = tid + i * 256;
        int row = id >> 4, cc = id & 15;
        int n = n0 + row;
        short8 v = {0, 0, 0, 0, 0, 0, 0, 0};
        if (n < N_NODES) v = *(const short8*)(U + (size_t)n * 128 + cc * 8);
        *(short8*)(sBuf + row * 136 + cc * 8) = v;
    }
    __syncthreads();

    floatx4 acc1[4][4];
#pragma unroll
    for (int rf = 0; rf < 4; ++rf)
#pragma unroll
        for (int cf = 0; cf < 4; ++cf) acc1[rf][cf] = (floatx4){0.f, 0.f, 0.f, 0.f};

#pragma unroll
    for (int kb = 0; kb < 4; ++kb) {
        short8 bfr[4];
#pragma unroll
        for (int cf = 0; cf < 4; ++cf) bfr[cf] = Wp1[(kb * 16 + w * 4 + cf) * 64 + lane];
        short8 af[4];
#pragma unroll
        for (int rf = 0; rf < 4; ++rf)
            af[rf] = *(const short8*)(sBuf + (rf * 16 + c15) * 136 + kb * 32 + g * 8);
#pragma unroll
        for (int rf = 0; rf < 4; ++rf)
#pragma unroll
            for (int cf = 0; cf < 4; ++cf)
                acc1[rf][cf] = __builtin_amdgcn_mfma_f32_16x16x32_bf16(af[rf], bfr[cf], acc1[rf][cf], 0, 0, 0);
    }

    int colb = w * 64;
    float bv[4], gv[4], bbv[4];
#pragma unroll
    for (int cf = 0; cf < 4; ++cf) {
        int c = colb + cf * 16 + c15;
        bv[cf] = b1[c]; gv[cf] = mg[c]; bbv[cf] = mb[c];
    }
    float sS[4][4], sQ[4][4];
#pragma unroll
    for (int rf = 0; rf < 4; ++rf)
#pragma unroll
        for (int reg = 0; reg < 4; ++reg) {
            float s = 0.f, q = 0.f;
#pragma unroll
            for (int cf = 0; cf < 4; ++cf) {
                float v = acc1[rf][cf][reg] + bv[cf];
                acc1[rf][cf][reg] = v;
                s += v; q += v * v;
            }
            sS[rf][reg] = s; sQ[rf][reg] = q;
        }
#pragma unroll
    for (int off = 1; off < 16; off <<= 1)
#pragma unroll
        for (int rf = 0; rf < 4; ++rf)
#pragma unroll
            for (int reg = 0; reg < 4; ++reg) {
                sS[rf][reg] += __shfl_xor(sS[rf][reg], off, 64);
                sQ[rf][reg] += __shfl_xor(sQ[rf][reg], off, 64);
            }
    if (c15 == 0) {
#pragma unroll
        for (int rf = 0; rf < 4; ++rf)
#pragma unroll
            for (int reg = 0; reg < 4; ++reg) {
                int row = rf * 16 + g * 4 + reg;
                sStat[w][row][0] = sS[rf][reg];
                sStat[w][row][1] = sQ[rf][reg];
            }
    }
    __syncthreads();
    if (tid < 64) {
        float s = sStat[0][tid][0] + sStat[1][tid][0] + sStat[2][tid][0] + sStat[3][tid][0];
        float q = sStat[0][tid][1] + sStat[1][tid][1] + sStat[2][tid][1] + sStat[3][tid][1];
        float mean = s * (1.f / 256.f);
        float var = q * (1.f / 256.f) - mean * mean;
        sMV[tid][0] = mean;
        sMV[tid][1] = rsqrtf(var + LN_EPS);
    }
    __syncthreads();

#pragma unroll
    for (int rf = 0; rf < 4; ++rf)
#pragma unroll
        for (int reg = 0; reg < 4; ++reg) {
            int row = rf * 16 + g * 4 + reg;
            float mean = sMV[row][0], inv = sMV[row][1];
#pragma unroll
            for (int cf = 0; cf < 4; ++cf) {
                float v = (acc1[rf][cf][reg] - mean) * inv * gv[cf] + bbv[cf];
                sBuf[row * 264 + colb + cf * 16 + c15] = f2bf(fmaxf(v, 0.f));
            }
        }
    __syncthreads();

    floatx4 acc2[4][2];
#pragma unroll
    for (int rf = 0; rf < 4; ++rf) {
        acc2[rf][0] = (floatx4){0.f, 0.f, 0.f, 0.f};
        acc2[rf][1] = (floatx4){0.f, 0.f, 0.f, 0.f};
    }
#pragma unroll
    for (int kb = 0; kb < 8; ++kb) {
        short8 bfr[2];
#pragma unroll
        for (int cf = 0; cf < 2; ++cf) bfr[cf] = Wp2[(kb * 8 + w * 2 + cf) * 64 + lane];
        short8 af[4];
#pragma unroll
        for (int rf = 0; rf < 4; ++rf)
            af[rf] = *(const short8*)(sBuf + (rf * 16 + c15) * 264 + kb * 32 + g * 8);
#pragma unroll
        for (int rf = 0; rf < 4; ++rf)
#pragma unroll
            for (int cf = 0; cf < 2; ++cf)
                acc2[rf][cf] = __builtin_amdgcn_mfma_f32_16x16x32_bf16(af[rf], bfr[cf], acc2[rf][cf], 0, 0, 0);
    }

    float b2v[2];
    b2v[0] = b2[w * 32 + c15];
    b2v[1] = b2[w * 32 + 16 + c15];
    float gn[2] = {0.f, 0.f}, bn[2] = {0.f, 0.f};
    if (writeHb) {
        gn[0] = nlg[w * 32 + c15];      bn[0] = nlb[w * 32 + c15];
        gn[1] = nlg[w * 32 + 16 + c15]; bn[1] = nlb[w * 32 + 16 + c15];
    }
#pragma unroll
    for (int rf = 0; rf < 4; ++rf)
#pragma unroll
        for (int reg = 0; reg < 4; ++reg) {
            int row = rf * 16 + g * 4 + reg;
            int n = n0 + row;
            float s = 0.f, q = 0.f;
#pragma unroll
            for (int cf = 0; cf < 2; ++cf) {
                float xold = (n < N_NODES) ? X[(size_t)n * 128 + w * 32 + cf * 16 + c15] : 0.f;
                float v = xold + acc2[rf][cf][reg] + b2v[cf];
                acc2[rf][cf][reg] = v;
                s += v; q += v * v;
            }
            if (writeHb) {
#pragma unroll
                for (int off = 1; off < 16; off <<= 1) {
                    s += __shfl_xor(s, off, 64);
                    q += __shfl_xor(q, off, 64);
                }
                if (c15 == 0) {
                    sStat[w][row][0] = s;
                    sStat[w][row][1] = q;
                }
            }
        }
    if (writeHb) {
        __syncthreads();
        if (tid < 64) {
            float s = sStat[0][tid][0] + sStat[1][tid][0] + sStat[2][tid][0] + sStat[3][tid][0];
            float q = sStat[0][tid][1] + sStat[1][tid][1] + sStat[2][tid][1] + sStat[3][tid][1];
            float mean = s * (1.f / 128.f);
            float var = q * (1.f / 128.f) - mean * mean;
            sMV[tid][0] = mean;
            sMV[tid][1] = rsqrtf(var + LN_EPS);
        }
        __syncthreads();
    }
#pragma unroll
    for (int rf = 0; rf < 4; ++rf)
#pragma unroll
        for (int reg = 0; reg < 4; ++reg) {
            int row = rf * 16 + g * 4 + reg;
            int n = n0 + row;
            if (n < N_NODES) {
                float mean = 0.f, inv = 0.f;
                if (writeHb) { mean = sMV[row][0]; inv = sMV[row][1]; }
#pragma unroll
                for (int cf = 0; cf < 2; ++cf) {
                    int col = w * 32 + cf * 16 + c15;
                    float v = acc2[rf][cf][reg];
                    X[(size_t)n * 128 + col] = v;
                    if (writeHb) {
                        float h = (v - mean) * inv * gn[cf] + bn[cf];
                        HbOut[(size_t)n * 128 + col] = f2bf(fmaxf(h, 0.f));
                    }
                }
            }
        }
}

// ---------------- global add pool ----------------
__global__ void k_pool(const float* __restrict__ X, const int* __restrict__ batch,
                       float* __restrict__ out) {
    __shared__ int sBat[128];
    int c = threadIdx.x;
    int n0 = blockIdx.x * 128;
    int nend = n0 + 128; if (nend > N_NODES) nend = N_NODES;
    sBat[c] = (n0 + c < N_NODES) ? batch[n0 + c] : -1;
    __syncthreads();
    float acc = 0.f;
    int cur = sBat[0];
    for (int n = n0; n < nend; ++n) {
        int g = sBat[n - n0];
        if (g != cur) {
            atomicAdd(&out[cur * HDIM + c], acc);
            acc = 0.f;
            cur = g;
        }
        acc += X[(size_t)n * HDIM + c];
    }
    if (nend > n0) atomicAdd(&out[cur * HDIM + c], acc);
}

extern "C" void kernel_launch(void* const* d_in, const int* in_sizes, int n_in,
                              void* d_out, int out_size, void* d_ws, size_t ws_size,
                              hipStream_t stream) {
    const float* x_in   = (const float*)d_in[0];
    const int*   eidx   = (const int*)d_in[1];
    const int*   batch  = (const int*)d_in[2];
    const float* node_W = (const float*)d_in[3];
    const float* node_b = (const float*)d_in[4];
    const float* ln_g   = (const float*)d_in[5];
    const float* ln_b   = (const float*)d_in[6];
    const float* t_all  = (const float*)d_in[7];
    const float* W1     = (const float*)d_in[8];
    const float* b1     = (const float*)d_in[9];
    const float* mg     = (const float*)d_in[10];
    const float* mb     = (const float*)d_in[11];
    const float* W2     = (const float*)d_in[12];
    const float* b2     = (const float*)d_in[13];
    float* out = (float*)d_out;

    char* ws = (char*)d_ws;
    float*  X   = (float*)(ws + 0);              // 25,600,000 B
    ushort2* Hb = (ushort2*)(ws + 25600000);     // 12,800,000 B
    ushort2* U  = (ushort2*)(ws + 38400000);     // 12,800,000 B
    ushort* Wp1 = (ushort*)(ws + 51200000);      // 393,216 B
    ushort* Wp2 = (ushort*)(ws + 51600000);      // 393,216 B
    int* deg     = (int*)(ws + 52000000);        // 200,000 B
    int* row_ptr = (int*)(ws + 52200064);        // 200,004 B
    int* cursor  = (int*)(ws + 52400128);        // 200,000 B
    ushort* csr_src = (ushort*)(ws + 52600192);  // 1,600,000 B
    int* bsum    = (int*)(ws + 54400192);        // 256 B

    const int* e_src = eidx;
    const int* e_dst = eidx + N_EDGES;

    hipMemsetAsync(deg, 0, N_NODES * sizeof(int), stream);
    k_hist<<<(N_EDGES + 255) / 256, 256, 0, stream>>>(e_dst, deg);
    k_bsum<<<SCAN_NB, 1024, 0, stream>>>(deg, bsum);
    k_scan_small<<<1, 64, 0, stream>>>(bsum);
    k_scan_final<<<SCAN_NB, 1024, 0, stream>>>(deg, bsum, row_ptr, cursor);
    k_scatter<<<(N_EDGES + 255) / 256, 256, 0, stream>>>(e_src, e_dst, cursor, csr_src);
    k_prep<<<192, 256, 0, stream>>>(W1, W2, Wp1, Wp2);
    k_encode_ln<<<12500, 256, 0, stream>>>(x_in, node_W, node_b, ln_g, ln_b, X, Hb);

    for (int l = 0; l < NLAYERS; ++l) {
        k_aggr<<<12500, 256, 0, stream>>>((const ushort*)Hb, row_ptr, csr_src, t_all, l,
                                          (ushort*)U);
        int wh = (l < NLAYERS - 1) ? 1 : 0;
        const float* nlg = ln_g + (wh ? (l + 1) : 0) * HDIM;
        const float* nlb = ln_b + (wh ? (l + 1) : 0) * HDIM;
        k_mlp_fused<<<(N_NODES + 63) / 64, 256, 0, stream>>>(
            (const ushort*)U, X,
            (const short8*)(Wp1 + (size_t)l * 32768), (const short8*)(Wp2 + (size_t)l * 32768),
            b1 + l * 256, mg + l * 256, mb + l * 256, b2 + l * 128,
            nlg, nlb, (ushort*)Hb, wh);
    }

    hipMemsetAsync(out, 0, NUM_GRAPHS * HDIM * sizeof(float), stream);
    k_pool<<<(N_NODES + 127) / 128, 128, 0, stream>>>(X, batch, out);
}

// Round 9
// 797.887 us; speedup vs baseline: 1.0089x; 1.0089x over previous
//
#include <hip/hip_runtime.h>
#include <hip/hip_bf16.h>
#include <math.h>

#define N_NODES 50000
#define N_EDGES 800000
#define IN_FEAT 8
#define HDIM 128
#define NLAYERS 6
#define NUM_GRAPHS 64
#define EPS_MSG 1e-7f
#define EPS_SM 1e-16f
#define LN_EPS 1e-5f
#define SCAN_NB 49   // ceil(50000/1024)

typedef __attribute__((ext_vector_type(8))) short short8;
typedef __attribute__((ext_vector_type(4))) float floatx4;
typedef __attribute__((ext_vector_type(2))) float floatx2;

__device__ __forceinline__ ushort f2bf(float x) {
    __hip_bfloat16 h = __float2bfloat16(x);
    return *reinterpret_cast<ushort*>(&h);
}
__device__ __forceinline__ float bf2f(ushort u) {
    unsigned int v = ((unsigned int)u) << 16;
    return __uint_as_float(v);
}
// pack two floats -> two fp8 e4m3 bytes (low word), RNE in HW
__device__ __forceinline__ ushort pk_fp8(float a, float b) {
    int r = __builtin_amdgcn_cvt_pk_fp8_f32(a, b, 0, false);
    return (ushort)(r & 0xffff);
}
__device__ __forceinline__ floatx2 upk_fp8(ushort v) {
    return __builtin_amdgcn_cvt_pk_f32_fp8((int)(unsigned)v, false);
}

// ---------------- node encoder + LN + ReLU (layer 0): X(bf16), Hb(fp8) ----------------
__global__ void k_encode_ln(const float* __restrict__ xin, const float* __restrict__ W,
                            const float* __restrict__ bias, const float* __restrict__ g0,
                            const float* __restrict__ b0, ushort* __restrict__ X,
                            ushort* __restrict__ Hb8) {
    __shared__ float sW[IN_FEAT * HDIM];
    int tid = threadIdx.x;
    int wid = tid >> 6, lane = tid & 63;
    for (int i = tid; i < IN_FEAT * HDIM; i += 256) sW[i] = W[i];
    __syncthreads();
    int n = blockIdx.x * 4 + wid;
    if (n >= N_NODES) return;
    int c0 = 2 * lane, c1 = 2 * lane + 1;
    float a0 = bias[c0], a1 = bias[c1];
#pragma unroll
    for (int f = 0; f < IN_FEAT; ++f) {
        float xf = xin[n * IN_FEAT + f];
        a0 += xf * sW[f * HDIM + c0];
        a1 += xf * sW[f * HDIM + c1];
    }
    ushort2 xv; xv.x = f2bf(a0); xv.y = f2bf(a1);
    *(ushort2*)(X + (size_t)n * HDIM + c0) = xv;
    float s = a0 + a1, sq = a0 * a0 + a1 * a1;
#pragma unroll
    for (int off = 32; off; off >>= 1) {
        s += __shfl_xor(s, off, 64);
        sq += __shfl_xor(sq, off, 64);
    }
    float mean = s * (1.f / 128.f);
    float var = sq * (1.f / 128.f) - mean * mean;
    float inv = rsqrtf(var + LN_EPS);
    float h0 = (a0 - mean) * inv * g0[c0] + b0[c0];
    float h1 = (a1 - mean) * inv * g0[c1] + b0[c1];
    Hb8[(size_t)n * 64 + lane] = pk_fp8(fmaxf(h0, 0.f), fmaxf(h1, 0.f));
}

// ---------------- CSR build ----------------
__global__ void k_hist(const int* __restrict__ dst, int* __restrict__ deg) {
    int i = blockIdx.x * blockDim.x + threadIdx.x;
    if (i < N_EDGES) atomicAdd(&deg[dst[i]], 1);
}

__global__ void k_bsum(const int* __restrict__ deg, int* __restrict__ bsum) {
    int i = blockIdx.x * 1024 + threadIdx.x;
    int v = (i < N_NODES) ? deg[i] : 0;
#pragma unroll
    for (int off = 32; off; off >>= 1) v += __shfl_xor(v, off, 64);
    __shared__ int wsum[16];
    int wid = threadIdx.x >> 6;
    if ((threadIdx.x & 63) == 0) wsum[wid] = v;
    __syncthreads();
    if (threadIdx.x < 16) {
        int s = wsum[threadIdx.x];
#pragma unroll
        for (int off = 8; off; off >>= 1) s += __shfl_xor(s, off, 16);
        if (threadIdx.x == 0) bsum[blockIdx.x] = s;
    }
}

__global__ void k_scan_small(int* __restrict__ bsum) {
    int lane = threadIdx.x;  // 0..63
    int orig = (lane < SCAN_NB) ? bsum[lane] : 0;
    int v = orig;
#pragma unroll
    for (int off = 1; off < 64; off <<= 1) {
        int u = __shfl_up(v, off, 64);
        if (lane >= off) v += u;
    }
    if (lane < SCAN_NB) bsum[lane] = v - orig;  // exclusive
}

__global__ void k_scan_final(const int* __restrict__ deg, const int* __restrict__ bsum,
                             int* __restrict__ row_ptr, int* __restrict__ cursor) {
    __shared__ int wsum[16];
    int i = blockIdx.x * 1024 + threadIdx.x;
    int t = threadIdx.x;
    int lane = t & 63, wid = t >> 6;
    int orig = (i < N_NODES) ? deg[i] : 0;
    int v = orig;
#pragma unroll
    for (int off = 1; off < 64; off <<= 1) {
        int u = __shfl_up(v, off, 64);
        if (lane >= off) v += u;
    }
    if (lane == 63) wsum[wid] = v;
    __syncthreads();
    if (t < 16) {
        int s = wsum[t];
#pragma unroll
        for (int off = 1; off < 16; off <<= 1) {
            int u = __shfl_up(s, off, 16);
            if (t >= off) s += u;
        }
        wsum[t] = s;
    }
    __syncthreads();
    int base = bsum[blockIdx.x] + (wid ? wsum[wid - 1] : 0);
    int excl = base + v - orig;
    if (i < N_NODES) {
        row_ptr[i] = excl;
        cursor[i] = excl;
    }
    if (i == 0) row_ptr[N_NODES] = N_EDGES;
}

__global__ void k_scatter(const int* __restrict__ src, const int* __restrict__ dst,
                          int* __restrict__ cursor, ushort* __restrict__ csr_src) {
    int i = blockIdx.x * blockDim.x + threadIdx.x;
    if (i < N_EDGES) {
        int pos = atomicAdd(&cursor[dst[i]], 1);
        csr_src[pos] = (ushort)src[i];
    }
}

// ---------------- weight prefragment: fp32 -> bf16 MFMA B-frag layout ----------------
__global__ void k_prep(const float* __restrict__ W1, const float* __restrict__ W2,
                       ushort* __restrict__ Wp1, ushort* __restrict__ Wp2) {
    int idx = blockIdx.x * 256 + threadIdx.x;
    if (idx < 24576) {
        int lane = idx & 63;
        int frag = idx >> 6;
        int cf = frag & 15, kb = (frag >> 4) & 3, l = frag >> 6;
        const float* Wl = W1 + (size_t)l * 128 * 256;
        ushort* o = Wp1 + (size_t)idx * 8;
        int k0 = kb * 32 + (lane >> 4) * 8;
        int c = cf * 16 + (lane & 15);
#pragma unroll
        for (int j = 0; j < 8; ++j) o[j] = f2bf(Wl[(k0 + j) * 256 + c]);
    } else if (idx < 49152) {
        int i2 = idx - 24576;
        int lane = i2 & 63;
        int frag = i2 >> 6;
        int cf = frag & 7, kb = (frag >> 3) & 7, l = frag >> 6;
        const float* Wl = W2 + (size_t)l * 256 * 128;
        ushort* o = Wp2 + (size_t)i2 * 8;
        int k0 = kb * 32 + (lane >> 4) * 8;
        int c = cf * 16 + (lane & 15);
#pragma unroll
        for (int j = 0; j < 8; ++j) o[j] = f2bf(Wl[(k0 + j) * 128 + c]);
    }
}

// ---------------- softmax aggregation: 2 waves/node, fp8 gather, U(bf16) = aggr + h ----------------
// No-shift exp valid: h bounded ~sqrt(127); exp(m*t) <= ~1e5 fp32-safe; softmax shift-invariant;
// num/den are plain sums so the two half-wave partials combine by addition.
__global__ __launch_bounds__(256) void k_aggr(const ushort* __restrict__ Hb8,
                                              const int* __restrict__ row_ptr,
                                              const ushort* __restrict__ csr,
                                              const float* __restrict__ t_all,
                                              int layer, ushort* __restrict__ U) {
    __shared__ float part[2][64][4];
    int tid = threadIdx.x;
    int wid = tid >> 6, lane = tid & 63;
    int local = wid >> 1;   // node slot (0..1)
    int half = wid & 1;     // edge-half
    int n = blockIdx.x * 2 + local;   // 25000*2 = 50000 exact
    float ts = t_all[layer] * 1.44269504f;  // exp(m t) = exp2(m ts)
    int beg = row_ptr[n], cnt = row_ptr[n + 1] - beg;
    int mycnt = (cnt - half + 1) >> 1;  // wave-uniform
    float den0 = 0.f, den1 = 0.f, num0 = 0.f, num1 = 0.f;

    auto RAW = [&](int k) -> ushort {
        int sidx = (int)csr[beg + half + 2 * k];
        return *(const ushort*)((const char*)Hb8 + (((unsigned)sidx) << 7) + (unsigned)(lane << 1));
    };
    auto proc = [&](ushort v) {
        floatx2 f = upk_fp8(v);
        float m0 = f.x + EPS_MSG;
        float m1 = f.y + EPS_MSG;
        float e0 = exp2f(m0 * ts);
        float e1 = exp2f(m1 * ts);
        den0 += e0; num0 = fmaf(m0, e0, num0);
        den1 += e1; num1 = fmaf(m1, e1, num1);
    };

    if (mycnt > 0) {
        ushort q0 = 0, q1 = 0, q2 = 0, q3 = 0, q4 = 0, q5 = 0, q6 = 0, q7 = 0;
        q0 = RAW(0);
        if (mycnt > 1) q1 = RAW(1);
        if (mycnt > 2) q2 = RAW(2);
        if (mycnt > 3) q3 = RAW(3);
        if (mycnt > 4) q4 = RAW(4);
        if (mycnt > 5) q5 = RAW(5);
        if (mycnt > 6) q6 = RAW(6);
        if (mycnt > 7) q7 = RAW(7);
        int p = 0;
        while (p + 8 <= mycnt) {
            ushort c0 = q0, c1 = q1, c2 = q2, c3 = q3,
                   c4 = q4, c5 = q5, c6 = q6, c7 = q7;
            if (p + 8 < mycnt)  q0 = RAW(p + 8);
            if (p + 9 < mycnt)  q1 = RAW(p + 9);
            if (p + 10 < mycnt) q2 = RAW(p + 10);
            if (p + 11 < mycnt) q3 = RAW(p + 11);
            if (p + 12 < mycnt) q4 = RAW(p + 12);
            if (p + 13 < mycnt) q5 = RAW(p + 13);
            if (p + 14 < mycnt) q6 = RAW(p + 14);
            if (p + 15 < mycnt) q7 = RAW(p + 15);
            proc(c0); proc(c1); proc(c2); proc(c3);
            proc(c4); proc(c5); proc(c6); proc(c7);
            p += 8;
        }
        int rem = mycnt - p;
        if (rem > 0) proc(q0);
        if (rem > 1) proc(q1);
        if (rem > 2) proc(q2);
        if (rem > 3) proc(q3);
        if (rem > 4) proc(q4);
        if (rem > 5) proc(q5);
        if (rem > 6) proc(q6);
    }

    if (half == 1) {
        part[local][lane][0] = num0;
        part[local][lane][1] = num1;
        part[local][lane][2] = den0;
        part[local][lane][3] = den1;
    }
    __syncthreads();
    if (half == 0) {
        num0 += part[local][lane][0];
        num1 += part[local][lane][1];
        den0 += part[local][lane][2];
        den1 += part[local][lane][3];
        floatx2 hs = upk_fp8(*(const ushort*)((const char*)Hb8 + (((unsigned)n) << 7) + (unsigned)(lane << 1)));
        ushort2 o;
        o.x = f2bf(num0 / (den0 + EPS_SM) + hs.x);
        o.y = f2bf(num1 / (den1 + EPS_SM) + hs.y);
        *(ushort2*)(U + (size_t)n * 128 + 2 * lane) = o;
    }
}

// ---- fused MLP: X(bf16) += W2^T(relu(LN(U@W1+b1)))+b2; epilogue LN+ReLU -> Hb8(next layer) ----
__global__ __launch_bounds__(256) void k_mlp_fused(
    const ushort* __restrict__ U, ushort* __restrict__ X,
    const short8* __restrict__ Wp1, const short8* __restrict__ Wp2,
    const float* __restrict__ b1, const float* __restrict__ mg,
    const float* __restrict__ mb, const float* __restrict__ b2,
    const float* __restrict__ nlg, const float* __restrict__ nlb,
    unsigned char* __restrict__ Hb8Out, int writeHb) {
    __shared__ ushort sBuf[64 * 264];
    __shared__ float sStat[4][64][2];
    __shared__ float sMV[64][2];
    int tid = threadIdx.x;
    int w = tid >> 6, lane = tid & 63;
    int g = lane >> 4, c15 = lane & 15;
    int n0 = blockIdx.x * 64;

#pragma unroll
    for (int i = 0; i < 4; ++i) {
        int id = tid + i * 256;
        int row = id >> 4, cc = id & 15;
        int n = n0 + row;
        short8 v = {0, 0, 0, 0, 0, 0, 0, 0};
        if (n < N_NODES) v = *(const short8*)(U + (size_t)n * 128 + cc * 8);
        *(short8*)(sBuf + row * 136 + cc * 8) = v;
    }
    __syncthreads();

    floatx4 acc1[4][4];
#pragma unroll
    for (int rf = 0; rf < 4; ++rf)
#pragma unroll
        for (int cf = 0; cf < 4; ++cf) acc1[rf][cf] = (floatx4){0.f, 0.f, 0.f, 0.f};

#pragma unroll
    for (int kb = 0; kb < 4; ++kb) {
        short8 bfr[4];
#pragma unroll
        for (int cf = 0; cf < 4; ++cf) bfr[cf] = Wp1[(kb * 16 + w * 4 + cf) * 64 + lane];
        short8 af[4];
#pragma unroll
        for (int rf = 0; rf < 4; ++rf)
            af[rf] = *(const short8*)(sBuf + (rf * 16 + c15) * 136 + kb * 32 + g * 8);
#pragma unroll
        for (int rf = 0; rf < 4; ++rf)
#pragma unroll
            for (int cf = 0; cf < 4; ++cf)
                acc1[rf][cf] = __builtin_amdgcn_mfma_f32_16x16x32_bf16(af[rf], bfr[cf], acc1[rf][cf], 0, 0, 0);
    }

    int colb = w * 64;
    float bv[4], gv[4], bbv[4];
#pragma unroll
    for (int cf = 0; cf < 4; ++cf) {
        int c = colb + cf * 16 + c15;
        bv[cf] = b1[c]; gv[cf] = mg[c]; bbv[cf] = mb[c];
    }
    float sS[4][4], sQ[4][4];
#pragma unroll
    for (int rf = 0; rf < 4; ++rf)
#pragma unroll
        for (int reg = 0; reg < 4; ++reg) {
            float s = 0.f, q = 0.f;
#pragma unroll
            for (int cf = 0; cf < 4; ++cf) {
                float v = acc1[rf][cf][reg] + bv[cf];
                acc1[rf][cf][reg] = v;
                s += v; q += v * v;
            }
            sS[rf][reg] = s; sQ[rf][reg] = q;
        }
#pragma unroll
    for (int off = 1; off < 16; off <<= 1)
#pragma unroll
        for (int rf = 0; rf < 4; ++rf)
#pragma unroll
            for (int reg = 0; reg < 4; ++reg) {
                sS[rf][reg] += __shfl_xor(sS[rf][reg], off, 64);
                sQ[rf][reg] += __shfl_xor(sQ[rf][reg], off, 64);
            }
    if (c15 == 0) {
#pragma unroll
        for (int rf = 0; rf < 4; ++rf)
#pragma unroll
            for (int reg = 0; reg < 4; ++reg) {
                int row = rf * 16 + g * 4 + reg;
                sStat[w][row][0] = sS[rf][reg];
                sStat[w][row][1] = sQ[rf][reg];
            }
    }
    __syncthreads();
    if (tid < 64) {
        float s = sStat[0][tid][0] + sStat[1][tid][0] + sStat[2][tid][0] + sStat[3][tid][0];
        float q = sStat[0][tid][1] + sStat[1][tid][1] + sStat[2][tid][1] + sStat[3][tid][1];
        float mean = s * (1.f / 256.f);
        float var = q * (1.f / 256.f) - mean * mean;
        sMV[tid][0] = mean;
        sMV[tid][1] = rsqrtf(var + LN_EPS);
    }
    __syncthreads();

#pragma unroll
    for (int rf = 0; rf < 4; ++rf)
#pragma unroll
        for (int reg = 0; reg < 4; ++reg) {
            int row = rf * 16 + g * 4 + reg;
            float mean = sMV[row][0], inv = sMV[row][1];
#pragma unroll
            for (int cf = 0; cf < 4; ++cf) {
                float v = (acc1[rf][cf][reg] - mean) * inv * gv[cf] + bbv[cf];
                sBuf[row * 264 + colb + cf * 16 + c15] = f2bf(fmaxf(v, 0.f));
            }
        }
    __syncthreads();

    floatx4 acc2[4][2];
#pragma unroll
    for (int rf = 0; rf < 4; ++rf) {
        acc2[rf][0] = (floatx4){0.f, 0.f, 0.f, 0.f};
        acc2[rf][1] = (floatx4){0.f, 0.f, 0.f, 0.f};
    }
#pragma unroll
    for (int kb = 0; kb < 8; ++kb) {
        short8 bfr[2];
#pragma unroll
        for (int cf = 0; cf < 2; ++cf) bfr[cf] = Wp2[(kb * 8 + w * 2 + cf) * 64 + lane];
        short8 af[4];
#pragma unroll
        for (int rf = 0; rf < 4; ++rf)
            af[rf] = *(const short8*)(sBuf + (rf * 16 + c15) * 264 + kb * 32 + g * 8);
#pragma unroll
        for (int rf = 0; rf < 4; ++rf)
#pragma unroll
            for (int cf = 0; cf < 2; ++cf)
                acc2[rf][cf] = __builtin_amdgcn_mfma_f32_16x16x32_bf16(af[rf], bfr[cf], acc2[rf][cf], 0, 0, 0);
    }

    float b2v[2];
    b2v[0] = b2[w * 32 + c15];
    b2v[1] = b2[w * 32 + 16 + c15];
    float gn[2] = {0.f, 0.f}, bn[2] = {0.f, 0.f};
    if (writeHb) {
        gn[0] = nlg[w * 32 + c15];      bn[0] = nlb[w * 32 + c15];
        gn[1] = nlg[w * 32 + 16 + c15]; bn[1] = nlb[w * 32 + 16 + c15];
    }
#pragma unroll
    for (int rf = 0; rf < 4; ++rf)
#pragma unroll
        for (int reg = 0; reg < 4; ++reg) {
            int row = rf * 16 + g * 4 + reg;
            int n = n0 + row;
            float s = 0.f, q = 0.f;
#pragma unroll
            for (int cf = 0; cf < 2; ++cf) {
                float xold = (n < N_NODES) ? bf2f(X[(size_t)n * 128 + w * 32 + cf * 16 + c15]) : 0.f;
                float v = xold + acc2[rf][cf][reg] + b2v[cf];
                acc2[rf][cf][reg] = v;
                s += v; q += v * v;
            }
            if (writeHb) {
#pragma unroll
                for (int off = 1; off < 16; off <<= 1) {
                    s += __shfl_xor(s, off, 64);
                    q += __shfl_xor(q, off, 64);
                }
                if (c15 == 0) {
                    sStat[w][row][0] = s;
                    sStat[w][row][1] = q;
                }
            }
        }
    if (writeHb) {
        __syncthreads();
        if (tid < 64) {
            float s = sStat[0][tid][0] + sStat[1][tid][0] + sStat[2][tid][0] + sStat[3][tid][0];
            float q = sStat[0][tid][1] + sStat[1][tid][1] + sStat[2][tid][1] + sStat[3][tid][1];
            float mean = s * (1.f / 128.f);
            float var = q * (1.f / 128.f) - mean * mean;
            sMV[tid][0] = mean;
            sMV[tid][1] = rsqrtf(var + LN_EPS);
        }
        __syncthreads();
    }
#pragma unroll
    for (int rf = 0; rf < 4; ++rf)
#pragma unroll
        for (int reg = 0; reg < 4; ++reg) {
            int row = rf * 16 + g * 4 + reg;
            int n = n0 + row;
            if (n < N_NODES) {
                float mean = 0.f, inv = 0.f;
                if (writeHb) { mean = sMV[row][0]; inv = sMV[row][1]; }
#pragma unroll
                for (int cf = 0; cf < 2; ++cf) {
                    int col = w * 32 + cf * 16 + c15;
                    float v = acc2[rf][cf][reg];
                    X[(size_t)n * 128 + col] = f2bf(v);
                    if (writeHb) {
                        float h = fmaxf((v - mean) * inv * gn[cf] + bn[cf], 0.f);
                        int pk = __builtin_amdgcn_cvt_pk_fp8_f32(h, h, 0, false);
                        Hb8Out[(size_t)n * 128 + col] = (unsigned char)(pk & 0xff);
                    }
                }
            }
        }
}

// ---------------- global add pool (bf16 X) ----------------
__global__ void k_pool(const ushort* __restrict__ X, const int* __restrict__ batch,
                       float* __restrict__ out) {
    __shared__ int sBat[128];
    int c = threadIdx.x;
    int n0 = blockIdx.x * 128;
    int nend = n0 + 128; if (nend > N_NODES) nend = N_NODES;
    sBat[c] = (n0 + c < N_NODES) ? batch[n0 + c] : -1;
    __syncthreads();
    float acc = 0.f;
    int cur = sBat[0];
    for (int n = n0; n < nend; ++n) {
        int g = sBat[n - n0];
        if (g != cur) {
            atomicAdd(&out[cur * HDIM + c], acc);
            acc = 0.f;
            cur = g;
        }
        acc += bf2f(X[(size_t)n * HDIM + c]);
    }
    if (nend > n0) atomicAdd(&out[cur * HDIM + c], acc);
}

extern "C" void kernel_launch(void* const* d_in, const int* in_sizes, int n_in,
                              void* d_out, int out_size, void* d_ws, size_t ws_size,
                              hipStream_t stream) {
    const float* x_in   = (const float*)d_in[0];
    const int*   eidx   = (const int*)d_in[1];
    const int*   batch  = (const int*)d_in[2];
    const float* node_W = (const float*)d_in[3];
    const float* node_b = (const float*)d_in[4];
    const float* ln_g   = (const float*)d_in[5];
    const float* ln_b   = (const float*)d_in[6];
    const float* t_all  = (const float*)d_in[7];
    const float* W1     = (const float*)d_in[8];
    const float* b1     = (const float*)d_in[9];
    const float* mg     = (const float*)d_in[10];
    const float* mb     = (const float*)d_in[11];
    const float* W2     = (const float*)d_in[12];
    const float* b2     = (const float*)d_in[13];
    float* out = (float*)d_out;

    char* ws = (char*)d_ws;
    ushort* X    = (ushort*)(ws + 0);            // 12,800,000 B (bf16)
    ushort* Hb8  = (ushort*)(ws + 12800000);     // 6,400,000 B (fp8, viewed as ushort pairs)
    ushort* U    = (ushort*)(ws + 19200000);     // 12,800,000 B (bf16)
    ushort* Wp1  = (ushort*)(ws + 32000000);     // 393,216 B
    ushort* Wp2  = (ushort*)(ws + 32400000);     // 393,216 B
    int* deg     = (int*)(ws + 32800000);        // 200,000 B
    int* row_ptr = (int*)(ws + 33000064);        // 200,004 B
    int* cursor  = (int*)(ws + 33200128);        // 200,000 B
    ushort* csr_src = (ushort*)(ws + 33400192);  // 1,600,000 B
    int* bsum    = (int*)(ws + 35000192);        // 256 B

    const int* e_src = eidx;
    const int* e_dst = eidx + N_EDGES;

    hipMemsetAsync(deg, 0, N_NODES * sizeof(int), stream);
    k_hist<<<(N_EDGES + 255) / 256, 256, 0, stream>>>(e_dst, deg);
    k_bsum<<<SCAN_NB, 1024, 0, stream>>>(deg, bsum);
    k_scan_small<<<1, 64, 0, stream>>>(bsum);
    k_scan_final<<<SCAN_NB, 1024, 0, stream>>>(deg, bsum, row_ptr, cursor);
    k_scatter<<<(N_EDGES + 255) / 256, 256, 0, stream>>>(e_src, e_dst, cursor, csr_src);
    k_prep<<<192, 256, 0, stream>>>(W1, W2, Wp1, Wp2);
    k_encode_ln<<<12500, 256, 0, stream>>>(x_in, node_W, node_b, ln_g, ln_b, X, Hb8);

    for (int l = 0; l < NLAYERS; ++l) {
        k_aggr<<<25000, 256, 0, stream>>>(Hb8, row_ptr, csr_src, t_all, l, U);
        int wh = (l < NLAYERS - 1) ? 1 : 0;
        const float* nlg = ln_g + (wh ? (l + 1) : 0) * HDIM;
        const float* nlb = ln_b + (wh ? (l + 1) : 0) * HDIM;
        k_mlp_fused<<<(N_NODES + 63) / 64, 256, 0, stream>>>(
            U, X,
            (const short8*)(Wp1 + (size_t)l * 32768), (const short8*)(Wp2 + (size_t)l * 32768),
            b1 + l * 256, mg + l * 256, mb + l * 256, b2 + l * 128,
            nlg, nlb, (unsigned char*)Hb8, wh);
    }

    hipMemsetAsync(out, 0, NUM_GRAPHS * HDIM * sizeof(float), stream);
    k_pool<<<(N_NODES + 127) / 128, 128, 0, stream>>>(X, batch, out);
}

// Round 10
// 707.820 us; speedup vs baseline: 1.1373x; 1.1272x over previous
//
#include <hip/hip_runtime.h>
#include <hip/hip_bf16.h>
#include <math.h>

#define N_NODES 50000
#define N_EDGES 800000
#define IN_FEAT 8
#define HDIM 128
#define NLAYERS 6
#define NUM_GRAPHS 64
#define EPS_MSG 1e-7f
#define EPS_SM 1e-16f
#define LN_EPS 1e-5f
#define SCAN_NB 49       // ceil(50000/1024)
#define DUMMY_ROW 50115  // 0xC3C3
#define CSR_CAP 1600000  // >= sum of padded degrees (<=1.55M)

typedef __attribute__((ext_vector_type(8))) short short8;
typedef __attribute__((ext_vector_type(4))) float floatx4;
typedef __attribute__((ext_vector_type(2))) float floatx2;

__device__ __forceinline__ ushort f2bf(float x) {
    __hip_bfloat16 h = __float2bfloat16(x);
    return *reinterpret_cast<ushort*>(&h);
}
__device__ __forceinline__ float bf2f(ushort u) {
    unsigned int v = ((unsigned int)u) << 16;
    return __uint_as_float(v);
}
__device__ __forceinline__ ushort pk_fp8(float a, float b) {
    int r = __builtin_amdgcn_cvt_pk_fp8_f32(a, b, 0, false);
    return (ushort)(r & 0xffff);
}
__device__ __forceinline__ floatx2 upk_fp8(ushort v) {
    return __builtin_amdgcn_cvt_pk_f32_fp8((int)(unsigned)v, false);
}

// ---------------- node encoder + LN + ReLU (layer 0): X(bf16), Hb(fp8) ----------------
__global__ void k_encode_ln(const float* __restrict__ xin, const float* __restrict__ W,
                            const float* __restrict__ bias, const float* __restrict__ g0,
                            const float* __restrict__ b0, ushort* __restrict__ X,
                            ushort* __restrict__ Hb8) {
    __shared__ float sW[IN_FEAT * HDIM];
    int tid = threadIdx.x;
    int wid = tid >> 6, lane = tid & 63;
    for (int i = tid; i < IN_FEAT * HDIM; i += 256) sW[i] = W[i];
    __syncthreads();
    int n = blockIdx.x * 4 + wid;
    if (n >= N_NODES) return;
    int c0 = 2 * lane, c1 = 2 * lane + 1;
    float a0 = bias[c0], a1 = bias[c1];
#pragma unroll
    for (int f = 0; f < IN_FEAT; ++f) {
        float xf = xin[n * IN_FEAT + f];
        a0 += xf * sW[f * HDIM + c0];
        a1 += xf * sW[f * HDIM + c1];
    }
    ushort2 xv; xv.x = f2bf(a0); xv.y = f2bf(a1);
    *(ushort2*)(X + (size_t)n * HDIM + c0) = xv;
    float s = a0 + a1, sq = a0 * a0 + a1 * a1;
#pragma unroll
    for (int off = 32; off; off >>= 1) {
        s += __shfl_xor(s, off, 64);
        sq += __shfl_xor(sq, off, 64);
    }
    float mean = s * (1.f / 128.f);
    float var = sq * (1.f / 128.f) - mean * mean;
    float inv = rsqrtf(var + LN_EPS);
    float h0 = (a0 - mean) * inv * g0[c0] + b0[c0];
    float h1 = (a1 - mean) * inv * g0[c1] + b0[c1];
    Hb8[(size_t)n * 64 + lane] = pk_fp8(fmaxf(h0, 0.f), fmaxf(h1, 0.f));
}

// ---------------- CSR build (padded-to-16 segments) ----------------
__global__ void k_hist(const int* __restrict__ dst, int* __restrict__ deg) {
    int i = blockIdx.x * blockDim.x + threadIdx.x;
    if (i < N_EDGES) atomicAdd(&deg[dst[i]], 1);
}

__global__ void k_bsum(const int* __restrict__ deg, int* __restrict__ bsum) {
    int i = blockIdx.x * 1024 + threadIdx.x;
    int v = (i < N_NODES) ? ((deg[i] + 15) & ~15) : 0;
#pragma unroll
    for (int off = 32; off; off >>= 1) v += __shfl_xor(v, off, 64);
    __shared__ int wsum[16];
    int wid = threadIdx.x >> 6;
    if ((threadIdx.x & 63) == 0) wsum[wid] = v;
    __syncthreads();
    if (threadIdx.x < 16) {
        int s = wsum[threadIdx.x];
#pragma unroll
        for (int off = 8; off; off >>= 1) s += __shfl_xor(s, off, 16);
        if (threadIdx.x == 0) bsum[blockIdx.x] = s;
    }
}

__global__ void k_scan_small(int* __restrict__ bsum) {
    int lane = threadIdx.x;  // 0..63
    int orig = (lane < SCAN_NB) ? bsum[lane] : 0;
    int v = orig;
#pragma unroll
    for (int off = 1; off < 64; off <<= 1) {
        int u = __shfl_up(v, off, 64);
        if (lane >= off) v += u;
    }
    if (lane < SCAN_NB) bsum[lane] = v - orig;  // exclusive
}

__global__ void k_scan_final(const int* __restrict__ deg, const int* __restrict__ bsum,
                             int* __restrict__ row_ptr, int* __restrict__ cursor) {
    __shared__ int wsum[16];
    int i = blockIdx.x * 1024 + threadIdx.x;
    int t = threadIdx.x;
    int lane = t & 63, wid = t >> 6;
    int orig = (i < N_NODES) ? ((deg[i] + 15) & ~15) : 0;
    int v = orig;
#pragma unroll
    for (int off = 1; off < 64; off <<= 1) {
        int u = __shfl_up(v, off, 64);
        if (lane >= off) v += u;
    }
    if (lane == 63) wsum[wid] = v;
    __syncthreads();
    if (t < 16) {
        int s = wsum[t];
#pragma unroll
        for (int off = 1; off < 16; off <<= 1) {
            int u = __shfl_up(s, off, 16);
            if (t >= off) s += u;
        }
        wsum[t] = s;
    }
    __syncthreads();
    int base = bsum[blockIdx.x] + (wid ? wsum[wid - 1] : 0);
    int excl = base + v - orig;
    if (i < N_NODES) {
        row_ptr[i] = excl;
        cursor[i] = excl;
        if (i == N_NODES - 1) row_ptr[N_NODES] = excl + orig;
    }
}

__global__ void k_scatter(const int* __restrict__ src, const int* __restrict__ dst,
                          int* __restrict__ cursor, ushort* __restrict__ csr_src) {
    int i = blockIdx.x * blockDim.x + threadIdx.x;
    if (i < N_EDGES) {
        int pos = atomicAdd(&cursor[dst[i]], 1);
        csr_src[pos] = (ushort)src[i];
    }
}

// ---------------- weight prefragment: fp32 -> bf16 MFMA B-frag layout ----------------
__global__ void k_prep(const float* __restrict__ W1, const float* __restrict__ W2,
                       ushort* __restrict__ Wp1, ushort* __restrict__ Wp2) {
    int idx = blockIdx.x * 256 + threadIdx.x;
    if (idx < 24576) {
        int lane = idx & 63;
        int frag = idx >> 6;
        int cf = frag & 15, kb = (frag >> 4) & 3, l = frag >> 6;
        const float* Wl = W1 + (size_t)l * 128 * 256;
        ushort* o = Wp1 + (size_t)idx * 8;
        int k0 = kb * 32 + (lane >> 4) * 8;
        int c = cf * 16 + (lane & 15);
#pragma unroll
        for (int j = 0; j < 8; ++j) o[j] = f2bf(Wl[(k0 + j) * 256 + c]);
    } else if (idx < 49152) {
        int i2 = idx - 24576;
        int lane = i2 & 63;
        int frag = i2 >> 6;
        int cf = frag & 7, kb = (frag >> 3) & 7, l = frag >> 6;
        const float* Wl = W2 + (size_t)l * 256 * 128;
        ushort* o = Wp2 + (size_t)i2 * 8;
        int k0 = kb * 32 + (lane >> 4) * 8;
        int c = cf * 16 + (lane & 15);
#pragma unroll
        for (int j = 0; j < 8; ++j) o[j] = f2bf(Wl[(k0 + j) * 128 + c]);
    }
}

// ---------------- softmax aggregation: 2 waves/node, padded guard-free loop ----------------
// Dummy slots hold src=DUMMY_ROW whose fp8 row is -256 => exp2 = 0 exactly (zero contribution).
// EPS_MSG deferred: e = exp2(f*ts) (uniform-scale-invariant); num += EPS*den at the end.
__global__ __launch_bounds__(256) void k_aggr(const ushort* __restrict__ Hb8,
                                              const int* __restrict__ row_ptr,
                                              const ushort* __restrict__ csr,
                                              const float* __restrict__ t_all,
                                              int layer, ushort* __restrict__ U) {
    __shared__ float part[2][64][4];
    int tid = threadIdx.x;
    int wid = tid >> 6, lane = tid & 63;
    int local = wid >> 1;   // node slot (0..1)
    int half = wid & 1;     // edge-half
    int n = blockIdx.x * 2 + local;   // 25000*2 = 50000 exact
    float ts = t_all[layer] * 1.44269504f;
    int beg = row_ptr[n];
    int cntp = row_ptr[n + 1] - beg;   // multiple of 16
    int mycnt = cntp >> 1;             // multiple of 8
    int myBeg = beg + half * mycnt;    // contiguous halves
    float den0 = 0.f, den1 = 0.f, num0 = 0.f, num1 = 0.f;
    unsigned lo = (unsigned)(lane << 1);

    for (int p = 0; p < mycnt; p += 8) {
        short8 cs = *(const short8*)(csr + myBeg + p);  // 8 indices, one 16B load
        ushort q0, q1, q2, q3, q4, q5, q6, q7;
        q0 = *(const ushort*)((const char*)Hb8 + (((unsigned)(ushort)cs[0]) << 7) + lo);
        q1 = *(const ushort*)((const char*)Hb8 + (((unsigned)(ushort)cs[1]) << 7) + lo);
        q2 = *(const ushort*)((const char*)Hb8 + (((unsigned)(ushort)cs[2]) << 7) + lo);
        q3 = *(const ushort*)((const char*)Hb8 + (((unsigned)(ushort)cs[3]) << 7) + lo);
        q4 = *(const ushort*)((const char*)Hb8 + (((unsigned)(ushort)cs[4]) << 7) + lo);
        q5 = *(const ushort*)((const char*)Hb8 + (((unsigned)(ushort)cs[5]) << 7) + lo);
        q6 = *(const ushort*)((const char*)Hb8 + (((unsigned)(ushort)cs[6]) << 7) + lo);
        q7 = *(const ushort*)((const char*)Hb8 + (((unsigned)(ushort)cs[7]) << 7) + lo);
#define PROC(Q)                                  \
        {                                        \
            floatx2 f = upk_fp8(Q);              \
            float e0 = exp2f(f.x * ts);          \
            float e1 = exp2f(f.y * ts);          \
            den0 += e0; num0 = fmaf(f.x, e0, num0); \
            den1 += e1; num1 = fmaf(f.y, e1, num1); \
        }
        PROC(q0) PROC(q1) PROC(q2) PROC(q3)
        PROC(q4) PROC(q5) PROC(q6) PROC(q7)
#undef PROC
    }

    if (half == 1) {
        part[local][lane][0] = num0;
        part[local][lane][1] = num1;
        part[local][lane][2] = den0;
        part[local][lane][3] = den1;
    }
    __syncthreads();
    if (half == 0) {
        num0 += part[local][lane][0];
        num1 += part[local][lane][1];
        den0 += part[local][lane][2];
        den1 += part[local][lane][3];
        num0 = fmaf(EPS_MSG, den0, num0);
        num1 = fmaf(EPS_MSG, den1, num1);
        floatx2 hs = upk_fp8(*(const ushort*)((const char*)Hb8 + (((unsigned)n) << 7) + lo));
        ushort2 o;
        o.x = f2bf(num0 / (den0 + EPS_SM) + hs.x);
        o.y = f2bf(num1 / (den1 + EPS_SM) + hs.y);
        *(ushort2*)(U + (size_t)n * 128 + 2 * lane) = o;
    }
}

// ---- fused MLP: X(bf16) += W2^T(relu(LN(U@W1+b1)))+b2; epilogue LN+ReLU -> Hb8(next layer) ----
__global__ __launch_bounds__(256) void k_mlp_fused(
    const ushort* __restrict__ U, ushort* __restrict__ X,
    const short8* __restrict__ Wp1, const short8* __restrict__ Wp2,
    const float* __restrict__ b1, const float* __restrict__ mg,
    const float* __restrict__ mb, const float* __restrict__ b2,
    const float* __restrict__ nlg, const float* __restrict__ nlb,
    unsigned char* __restrict__ Hb8Out, int writeHb) {
    __shared__ ushort sBuf[64 * 264];
    __shared__ float sStat[4][64][2];
    __shared__ float sMV[64][2];
    int tid = threadIdx.x;
    int w = tid >> 6, lane = tid & 63;
    int g = lane >> 4, c15 = lane & 15;
    int n0 = blockIdx.x * 64;

#pragma unroll
    for (int i = 0; i < 4; ++i) {
        int id = tid + i * 256;
        int row = id >> 4, cc = id & 15;
        int n = n0 + row;
        short8 v = {0, 0, 0, 0, 0, 0, 0, 0};
        if (n < N_NODES) v = *(const short8*)(U + (size_t)n * 128 + cc * 8);
        *(short8*)(sBuf + row * 136 + cc * 8) = v;
    }
    __syncthreads();

    floatx4 acc1[4][4];
#pragma unroll
    for (int rf = 0; rf < 4; ++rf)
#pragma unroll
        for (int cf = 0; cf < 4; ++cf) acc1[rf][cf] = (floatx4){0.f, 0.f, 0.f, 0.f};

#pragma unroll
    for (int kb = 0; kb < 4; ++kb) {
        short8 bfr[4];
#pragma unroll
        for (int cf = 0; cf < 4; ++cf) bfr[cf] = Wp1[(kb * 16 + w * 4 + cf) * 64 + lane];
        short8 af[4];
#pragma unroll
        for (int rf = 0; rf < 4; ++rf)
            af[rf] = *(const short8*)(sBuf + (rf * 16 + c15) * 136 + kb * 32 + g * 8);
#pragma unroll
        for (int rf = 0; rf < 4; ++rf)
#pragma unroll
            for (int cf = 0; cf < 4; ++cf)
                acc1[rf][cf] = __builtin_amdgcn_mfma_f32_16x16x32_bf16(af[rf], bfr[cf], acc1[rf][cf], 0, 0, 0);
    }

    int colb = w * 64;
    float bv[4], gv[4], bbv[4];
#pragma unroll
    for (int cf = 0; cf < 4; ++cf) {
        int c = colb + cf * 16 + c15;
        bv[cf] = b1[c]; gv[cf] = mg[c]; bbv[cf] = mb[c];
    }
    float sS[4][4], sQ[4][4];
#pragma unroll
    for (int rf = 0; rf < 4; ++rf)
#pragma unroll
        for (int reg = 0; reg < 4; ++reg) {
            float s = 0.f, q = 0.f;
#pragma unroll
            for (int cf = 0; cf < 4; ++cf) {
                float v = acc1[rf][cf][reg] + bv[cf];
                acc1[rf][cf][reg] = v;
                s += v; q += v * v;
            }
            sS[rf][reg] = s; sQ[rf][reg] = q;
        }
#pragma unroll
    for (int off = 1; off < 16; off <<= 1)
#pragma unroll
        for (int rf = 0; rf < 4; ++rf)
#pragma unroll
            for (int reg = 0; reg < 4; ++reg) {
                sS[rf][reg] += __shfl_xor(sS[rf][reg], off, 64);
                sQ[rf][reg] += __shfl_xor(sQ[rf][reg], off, 64);
            }
    if (c15 == 0) {
#pragma unroll
        for (int rf = 0; rf < 4; ++rf)
#pragma unroll
            for (int reg = 0; reg < 4; ++reg) {
                int row = rf * 16 + g * 4 + reg;
                sStat[w][row][0] = sS[rf][reg];
                sStat[w][row][1] = sQ[rf][reg];
            }
    }
    __syncthreads();
    if (tid < 64) {
        float s = sStat[0][tid][0] + sStat[1][tid][0] + sStat[2][tid][0] + sStat[3][tid][0];
        float q = sStat[0][tid][1] + sStat[1][tid][1] + sStat[2][tid][1] + sStat[3][tid][1];
        float mean = s * (1.f / 256.f);
        float var = q * (1.f / 256.f) - mean * mean;
        sMV[tid][0] = mean;
        sMV[tid][1] = rsqrtf(var + LN_EPS);
    }
    __syncthreads();

#pragma unroll
    for (int rf = 0; rf < 4; ++rf)
#pragma unroll
        for (int reg = 0; reg < 4; ++reg) {
            int row = rf * 16 + g * 4 + reg;
            float mean = sMV[row][0], inv = sMV[row][1];
#pragma unroll
            for (int cf = 0; cf < 4; ++cf) {
                float v = (acc1[rf][cf][reg] - mean) * inv * gv[cf] + bbv[cf];
                sBuf[row * 264 + colb + cf * 16 + c15] = f2bf(fmaxf(v, 0.f));
            }
        }
    __syncthreads();

    floatx4 acc2[4][2];
#pragma unroll
    for (int rf = 0; rf < 4; ++rf) {
        acc2[rf][0] = (floatx4){0.f, 0.f, 0.f, 0.f};
        acc2[rf][1] = (floatx4){0.f, 0.f, 0.f, 0.f};
    }
#pragma unroll
    for (int kb = 0; kb < 8; ++kb) {
        short8 bfr[2];
#pragma unroll
        for (int cf = 0; cf < 2; ++cf) bfr[cf] = Wp2[(kb * 8 + w * 2 + cf) * 64 + lane];
        short8 af[4];
#pragma unroll
        for (int rf = 0; rf < 4; ++rf)
            af[rf] = *(const short8*)(sBuf + (rf * 16 + c15) * 264 + kb * 32 + g * 8);
#pragma unroll
        for (int rf = 0; rf < 4; ++rf)
#pragma unroll
            for (int cf = 0; cf < 2; ++cf)
                acc2[rf][cf] = __builtin_amdgcn_mfma_f32_16x16x32_bf16(af[rf], bfr[cf], acc2[rf][cf], 0, 0, 0);
    }

    float b2v[2];
    b2v[0] = b2[w * 32 + c15];
    b2v[1] = b2[w * 32 + 16 + c15];
    float gn[2] = {0.f, 0.f}, bn[2] = {0.f, 0.f};
    if (writeHb) {
        gn[0] = nlg[w * 32 + c15];      bn[0] = nlb[w * 32 + c15];
        gn[1] = nlg[w * 32 + 16 + c15]; bn[1] = nlb[w * 32 + 16 + c15];
    }
#pragma unroll
    for (int rf = 0; rf < 4; ++rf)
#pragma unroll
        for (int reg = 0; reg < 4; ++reg) {
            int row = rf * 16 + g * 4 + reg;
            int n = n0 + row;
            float s = 0.f, q = 0.f;
#pragma unroll
            for (int cf = 0; cf < 2; ++cf) {
                float xold = (n < N_NODES) ? bf2f(X[(size_t)n * 128 + w * 32 + cf * 16 + c15]) : 0.f;
                float v = xold + acc2[rf][cf][reg] + b2v[cf];
                acc2[rf][cf][reg] = v;
                s += v; q += v * v;
            }
            if (writeHb) {
#pragma unroll
                for (int off = 1; off < 16; off <<= 1) {
                    s += __shfl_xor(s, off, 64);
                    q += __shfl_xor(q, off, 64);
                }
                if (c15 == 0) {
                    sStat[w][row][0] = s;
                    sStat[w][row][1] = q;
                }
            }
        }
    if (writeHb) {
        __syncthreads();
        if (tid < 64) {
            float s = sStat[0][tid][0] + sStat[1][tid][0] + sStat[2][tid][0] + sStat[3][tid][0];
            float q = sStat[0][tid][1] + sStat[1][tid][1] + sStat[2][tid][1] + sStat[3][tid][1];
            float mean = s * (1.f / 128.f);
            float var = q * (1.f / 128.f) - mean * mean;
            sMV[tid][0] = mean;
            sMV[tid][1] = rsqrtf(var + LN_EPS);
        }
        __syncthreads();
    }
#pragma unroll
    for (int rf = 0; rf < 4; ++rf)
#pragma unroll
        for (int reg = 0; reg < 4; ++reg) {
            int row = rf * 16 + g * 4 + reg;
            int n = n0 + row;
            if (n < N_NODES) {
                float mean = 0.f, inv = 0.f;
                if (writeHb) { mean = sMV[row][0]; inv = sMV[row][1]; }
#pragma unroll
                for (int cf = 0; cf < 2; ++cf) {
                    int col = w * 32 + cf * 16 + c15;
                    float v = acc2[rf][cf][reg];
                    X[(size_t)n * 128 + col] = f2bf(v);
                    if (writeHb) {
                        float h = fmaxf((v - mean) * inv * gn[cf] + bn[cf], 0.f);
                        int pk = __builtin_amdgcn_cvt_pk_fp8_f32(h, h, 0, false);
                        Hb8Out[(size_t)n * 128 + col] = (unsigned char)(pk & 0xff);
                    }
                }
            }
        }
}

// ---------------- global add pool (bf16 X) ----------------
__global__ void k_pool(const ushort* __restrict__ X, const int* __restrict__ batch,
                       float* __restrict__ out) {
    __shared__ int sBat[128];
    int c = threadIdx.x;
    int n0 = blockIdx.x * 128;
    int nend = n0 + 128; if (nend > N_NODES) nend = N_NODES;
    sBat[c] = (n0 + c < N_NODES) ? batch[n0 + c] : -1;
    __syncthreads();
    float acc = 0.f;
    int cur = sBat[0];
    for (int n = n0; n < nend; ++n) {
        int g = sBat[n - n0];
        if (g != cur) {
            atomicAdd(&out[cur * HDIM + c], acc);
            acc = 0.f;
            cur = g;
        }
        acc += bf2f(X[(size_t)n * HDIM + c]);
    }
    if (nend > n0) atomicAdd(&out[cur * HDIM + c], acc);
}

extern "C" void kernel_launch(void* const* d_in, const int* in_sizes, int n_in,
                              void* d_out, int out_size, void* d_ws, size_t ws_size,
                              hipStream_t stream) {
    const float* x_in   = (const float*)d_in[0];
    const int*   eidx   = (const int*)d_in[1];
    const int*   batch  = (const int*)d_in[2];
    const float* node_W = (const float*)d_in[3];
    const float* node_b = (const float*)d_in[4];
    const float* ln_g   = (const float*)d_in[5];
    const float* ln_b   = (const float*)d_in[6];
    const float* t_all  = (const float*)d_in[7];
    const float* W1     = (const float*)d_in[8];
    const float* b1     = (const float*)d_in[9];
    const float* mg     = (const float*)d_in[10];
    const float* mb     = (const float*)d_in[11];
    const float* W2     = (const float*)d_in[12];
    const float* b2     = (const float*)d_in[13];
    float* out = (float*)d_out;

    char* ws = (char*)d_ws;
    ushort* X    = (ushort*)(ws + 0);            // 12,800,000 B (bf16)
    ushort* Hb8  = (ushort*)(ws + 12800000);     // 6,414,848 B (fp8, 50116 rows x 128B)
    ushort* U    = (ushort*)(ws + 19216000);     // 12,800,000 B (bf16)
    ushort* Wp1  = (ushort*)(ws + 32016000);     // 393,216 B
    ushort* Wp2  = (ushort*)(ws + 32416000);     // 393,216 B
    int* deg     = (int*)(ws + 32816000);        // 200,000 B
    int* row_ptr = (int*)(ws + 33016064);        // 200,004 B
    int* cursor  = (int*)(ws + 33216128);        // 200,000 B
    ushort* csr_src = (ushort*)(ws + 33416128);  // 3,200,000 B (padded CSR)
    int* bsum    = (int*)(ws + 36616128);        // 256 B

    const int* e_src = eidx;
    const int* e_dst = eidx + N_EDGES;

    hipMemsetAsync(deg, 0, N_NODES * sizeof(int), stream);
    hipMemsetAsync(csr_src, 0xC3, CSR_CAP * sizeof(ushort), stream);  // pad = DUMMY_ROW
    hipMemsetAsync((char*)Hb8 + (size_t)DUMMY_ROW * 128, 0xF8, 128, stream);  // fp8 -256 row
    k_hist<<<(N_EDGES + 255) / 256, 256, 0, stream>>>(e_dst, deg);
    k_bsum<<<SCAN_NB, 1024, 0, stream>>>(deg, bsum);
    k_scan_small<<<1, 64, 0, stream>>>(bsum);
    k_scan_final<<<SCAN_NB, 1024, 0, stream>>>(deg, bsum, row_ptr, cursor);
    k_scatter<<<(N_EDGES + 255) / 256, 256, 0, stream>>>(e_src, e_dst, cursor, csr_src);
    k_prep<<<192, 256, 0, stream>>>(W1, W2, Wp1, Wp2);
    k_encode_ln<<<12500, 256, 0, stream>>>(x_in, node_W, node_b, ln_g, ln_b, X, Hb8);

    for (int l = 0; l < NLAYERS; ++l) {
        k_aggr<<<25000, 256, 0, stream>>>(Hb8, row_ptr, csr_src, t_all, l, U);
        int wh = (l < NLAYERS - 1) ? 1 : 0;
        const float* nlg = ln_g + (wh ? (l + 1) : 0) * HDIM;
        const float* nlb = ln_b + (wh ? (l + 1) : 0) * HDIM;
        k_mlp_fused<<<(N_NODES + 63) / 64, 256, 0, stream>>>(
            U, X,
            (const short8*)(Wp1 + (size_t)l * 32768), (const short8*)(Wp2 + (size_t)l * 32768),
            b1 + l * 256, mg + l * 256, mb + l * 256, b2 + l * 128,
            nlg, nlb, (unsigned char*)Hb8, wh);
    }

    hipMemsetAsync(out, 0, NUM_GRAPHS * HDIM * sizeof(float), stream);
    k_pool<<<(N_NODES + 127) / 128, 128, 0, stream>>>(X, batch, out);
}